// Round 17
// baseline (418.004 us; speedup 1.0000x reference)
//
#include <hip/hip_runtime.h>
#include <hip/hip_bf16.h>
#include <cstdint>

typedef unsigned short u16;
typedef unsigned int   u32;
typedef __attribute__((ext_vector_type(8))) short bf16x8;   // 8 bf16 = 4 VGPRs
typedef __attribute__((ext_vector_type(4))) u32  u32x4;
typedef __attribute__((ext_vector_type(4))) float f32x4;

#define MFMA16(a,b,c)    __builtin_amdgcn_mfma_f32_16x16x32_bf16((a),(b),(c),0,0,0)

#define BSZ    4
#define SEQ    2048
#define DMODEL 1024
#define NHEAD  16
#define HDIM   64
#define MTOT   (BSZ*SEQ)   // 8192
#define MASKV  (-3.0e38f)  // finite: exp2(MASKV - m) == 0, no inf-inf NaN
#define NW     (DMODEL*DMODEL)

// native conversion (RNE)
__device__ __forceinline__ u16 f2bf(float f) {
  __hip_bfloat16 h = __float2bfloat16(f);
  return __builtin_bit_cast(u16, h);
}
// paired conversion -> v_cvt_pk_bf16_f32 (RNE)
__device__ __forceinline__ u32 f2bf2(float a, float b) {
  __hip_bfloat162 h = __float22bfloat162_rn(make_float2(a, b));
  u32 u; __builtin_memcpy(&u, &h, sizeof(u));
  return u;
}
// fmax-of-3 -> v_max3_f32
__device__ __forceinline__ float max3f(float a, float b, float c) {
  return fmaxf(fmaxf(a, b), c);
}

typedef __attribute__((address_space(1))) void g1v;
typedef __attribute__((address_space(3))) void l3v;
// async global->LDS, 16B/lane. LDS dest is wave-uniform base (HW adds lane*16B).
__device__ __forceinline__ void gload16(const void* g, void* l) {
  __builtin_amdgcn_global_load_lds((g1v*)(uintptr_t)g, (l3v*)(u32)(uintptr_t)l, 16, 0, 0);
}

// ---------------- pack: fp32 -> bf16 activations (x, ek, ev in one launch) ----------
__global__ void pack_act3(const float* __restrict__ x, const float* __restrict__ ek,
                          const float* __restrict__ ev, u16* __restrict__ xb,
                          u16* __restrict__ ekb, u16* __restrict__ evb, int n4) {
  int i = blockIdx.x * blockDim.x + threadIdx.x;
  if (i >= n4) return;
  const float* in; u16* out;
  if (blockIdx.y == 0)      { in = x;  out = xb;  }
  else if (blockIdx.y == 1) { in = ek; out = ekb; }
  else                      { in = ev; out = evb; }
  float4 v = ((const float4*)in)[i];
  ((uint2*)out)[i] = make_uint2(f2bf2(v.x, v.y), f2bf2(v.z, v.w));
}

// ---------------- pack: all 8 weights -> Bt[n][k] bf16 in one launch ----------------
__global__ void pack_w8(const float* __restrict__ w0, const float* __restrict__ w1,
                        const float* __restrict__ w2, const float* __restrict__ w3,
                        const float* __restrict__ w4, const float* __restrict__ w5,
                        const float* __restrict__ w6, const float* __restrict__ w7,
                        u16* __restrict__ wt) {
  __shared__ float tile[64][65];
  const int w = blockIdx.z;
  const float* src;
  switch (w) {
    case 0: src = w0; break; case 1: src = w1; break;
    case 2: src = w2; break; case 3: src = w3; break;
    case 4: src = w4; break; case 5: src = w5; break;
    case 6: src = w6; break; default: src = w7; break;
  }
  const int per_head = (w == 3 || w == 7) ? 0 : 1;
  u16* dst = wt + (size_t)w * NW;
  int kt = blockIdx.x * 64, nt = blockIdx.y * 64;
  int tx = threadIdx.x & 63, ty = threadIdx.x >> 6;
  for (int kk = ty; kk < 64; kk += 4) {
    int k = kt + kk, n = nt + tx;
    float v = per_head ? src[(size_t)(n >> 6) * (DMODEL * HDIM) + (size_t)k * HDIM + (n & 63)]
                       : src[(size_t)k * DMODEL + n];
    tile[kk][tx] = v;
  }
  __syncthreads();
  for (int nn = ty; nn < 64; nn += 4)
    dst[(size_t)(nt + nn) * DMODEL + kt + tx] = f2bf(tile[tx][nn]);
}

// ---------------- GEMM core (BK=64 double-buffered 2-phase prefetch) ----------------
// epi: 0 = bf16 [M][N]; 1 = bf16 Vt s-permuted; 2 = f32 [M][N]
template <bool TMPL>
__device__ __forceinline__ void gemm_body(const u16* __restrict__ A, const u16* __restrict__ Bt,
                                          const float* __restrict__ bias, void* __restrict__ Cout,
                                          float scale, int epi, int inner)
{
  __shared__ u16 As[2][128 * 64];
  __shared__ u16 Bs[2][128 * 64];
  const int lane = threadIdx.x & 63, wid = threadIdx.x >> 6;
  const int wg = ((inner & 7) << 6) | (inner >> 3);  // [xcd:3][seq:6]
  const int m0 = (wg >> 3) * 128, n0 = (wg & 7) * 128;

  const int srow = wid * 32 + (lane >> 3);          // +i*8; (row&7) == lane>>3
  const int sc = (lane & 7) ^ ((lane >> 3) & 7);    // pre-swizzled source chunk
  const u16* gA = A  + (size_t)(m0 + srow) * DMODEL + sc * 8;
  const u16* gB = Bt + (size_t)(n0 + srow) * DMODEL + sc * 8;

  const int fr = lane & 15, quad = lane >> 4;
  const int wr = (wid >> 1) * 64, wc = (wid & 1) * 64;

  f32x4 acc[4][4] = {};
  const int NT = DMODEL / 64;   // 16

#pragma unroll
  for (int i = 0; i < 4; ++i) {
    gload16(gA + (size_t)(i * 8) * DMODEL, &As[0][(wid * 32 + i * 8) * 64]);
    gload16(gB + (size_t)(i * 8) * DMODEL, &Bs[0][(wid * 32 + i * 8) * 64]);
  }
  gA += 64; gB += 64;
  __syncthreads();

  for (int kt = 0; kt < NT; ++kt) {
    const int cur = kt & 1;
    if (kt + 1 < NT) {
#pragma unroll
      for (int i = 0; i < 4; ++i) {
        gload16(gA + (size_t)(i * 8) * DMODEL, &As[cur ^ 1][(wid * 32 + i * 8) * 64]);
        gload16(gB + (size_t)(i * 8) * DMODEL, &Bs[cur ^ 1][(wid * 32 + i * 8) * 64]);
      }
      gA += 64; gB += 64;
    }
#pragma unroll
    for (int kp = 0; kp < 2; ++kp) {
      bf16x8 af[4], bfr[4];
#pragma unroll
      for (int i = 0; i < 4; ++i) {
        int ra = wr + i * 16 + fr;
        af[i]  = *(const bf16x8*)&As[cur][ra * 64 + (((kp * 4 + quad) ^ (ra & 7)) * 8)];
        int rb = wc + i * 16 + fr;
        bfr[i] = *(const bf16x8*)&Bs[cur][rb * 64 + (((kp * 4 + quad) ^ (rb & 7)) * 8)];
      }
#pragma unroll
      for (int i = 0; i < 4; ++i)
#pragma unroll
        for (int j = 0; j < 4; ++j)
          acc[i][j] = MFMA16(af[i], bfr[j], acc[i][j]);
    }
    __syncthreads();   // buf[cur] reads done; buf[cur^1] staging drained
  }

  // C/D layout: col = lane&15, row = (lane>>4)*4 + reg
#pragma unroll
  for (int i = 0; i < 4; ++i) {
    int row0 = m0 + wr + i * 16 + quad * 4;
#pragma unroll
    for (int j = 0; j < 4; ++j) {
      int col = n0 + wc + j * 16 + fr;
      float bv = bias[col];
      float v0 = (acc[i][j][0] + bv) * scale, v1 = (acc[i][j][1] + bv) * scale;
      float v2 = (acc[i][j][2] + bv) * scale, v3 = (acc[i][j][3] + bv) * scale;
      if (epi == 2) {
        float* C = (float*)Cout;
        C[(size_t)(row0 + 0) * DMODEL + col] = v0;
        C[(size_t)(row0 + 1) * DMODEL + col] = v1;
        C[(size_t)(row0 + 2) * DMODEL + col] = v2;
        C[(size_t)(row0 + 3) * DMODEL + col] = v3;
      } else if (epi == 0) {
        u16* C = (u16*)Cout;
        C[(size_t)(row0 + 0) * DMODEL + col] = f2bf(v0);
        C[(size_t)(row0 + 1) * DMODEL + col] = f2bf(v1);
        C[(size_t)(row0 + 2) * DMODEL + col] = f2bf(v2);
        C[(size_t)(row0 + 3) * DMODEL + col] = f2bf(v3);
      } else {
        u16* C = (u16*)Cout;
        int bi = row0 >> 11, s = row0 & 2047;
        // permuted s within 32-group: (b:1|c:2|r:2) -> (c:2|b:1|r:2)
        int sN = (s & ~31) | (((s >> 2) & 3) << 3) | (((s >> 4) & 1) << 2) | (s & 3);
        size_t vtr = ((size_t)(bi * NHEAD + (col >> 6)) * HDIM + (col & 63)) * SEQ + sN;
        *(uint2*)&C[vtr] = make_uint2(f2bf2(v0, v1), f2bf2(v2, v3));
      }
    }
  }
}

// single GEMM (Wo projections, final output)
__global__ __launch_bounds__(256, 2)
void gemm_bt(const u16* __restrict__ A, const u16* __restrict__ Bt,
             const float* __restrict__ bias, void* __restrict__ Cout,
             float scale, int epi)
{
  gemm_body<true>(A, Bt, bias, Cout, scale, epi, blockIdx.x);
}

// fused Q/K/V projections: 3 x 512 blocks; seg = bid>>9 picks operands (uniform)
__global__ __launch_bounds__(256, 2)
void gemm_qkv(const u16* __restrict__ Aq, const u16* __restrict__ Ak,
              const u16* __restrict__ Av, const u16* __restrict__ Btb,
              const float* __restrict__ bq, const float* __restrict__ bk,
              const float* __restrict__ bv, void* __restrict__ oq,
              void* __restrict__ ok, void* __restrict__ ov, float qscale)
{
  const int seg = blockIdx.x >> 9, inner = blockIdx.x & 511;
  const u16* A; const float* bias; void* Cout; float scale; int epi;
  if (seg == 0)      { A = Aq; bias = bq; Cout = oq; scale = qscale; epi = 0; }
  else if (seg == 1) { A = Ak; bias = bk; Cout = ok; scale = 1.0f;   epi = 0; }
  else               { A = Av; bias = bv; Cout = ov; scale = 1.0f;   epi = 1; }
  gemm_body<true>(A, Btb + (size_t)seg * NW, bias, Cout, scale, epi, inner);
}

// ---------------- flash attention v15 ----------------
// v14 + (a) launch_bounds(256,5): LDS allows exactly 5 blocks/CU; 5th resident
// block fills issue gaps in this issue-bound kernel. (b) compile-time-selected
// scalar LDS bases (no pointer arrays -> no scratch risk).
// Split-K waves 2x2, swapped QK^T, zero-shuffle P, K=32 PV, MFMA row-sum.
// Causal: 1024 paired blocks (uniform 33 steps). Cross: 2048 single-tile blocks.

#define ATTN_STEP(CUR, TT)                                                      \
  do {                                                                          \
    const int kb_ = (TT) * 64;                                                  \
    if ((TT) + 1 < nsteps) {                                                    \
      gload16(kpre,              &KV[(CUR) ^ 1][(wid * 16 + 0) * 64]);          \
      gload16(kpre + 8 * DMODEL, &KV[(CUR) ^ 1][(wid * 16 + 8) * 64]);          \
      gload16(vpre,              &KV[2 + ((CUR) ^ 1)][(wid * 16 + 0) * 64]);    \
      gload16(vpre + 8 * SEQ,    &KV[2 + ((CUR) ^ 1)][(wid * 16 + 8) * 64]);    \
      kpre += 64 * DMODEL; vpre += 64;                                          \
    }                                                                           \
    const u16* kr_ = (CUR) ? kB1 : kB0;                                         \
    f32x4 sa[2][2];                                                             \
    __builtin_amdgcn_s_setprio(1);                                              \
    {                                                                           \
      bf16x8 kfa = *(const bf16x8*)&kr_[xk0];                                   \
      bf16x8 kfb = *(const bf16x8*)&kr_[xk1];                                   \
      f32x4 s = {};                                                             \
      s = MFMA16(kfa, aq[0][0], s); s = MFMA16(kfb, aq[0][1], s); sa[0][0] = s; \
      s = (f32x4){};                                                            \
      s = MFMA16(kfa, aq[1][0], s); s = MFMA16(kfb, aq[1][1], s); sa[0][1] = s; \
      kfa = *(const bf16x8*)&kr_[16 * 64 + xk0];                                \
      kfb = *(const bf16x8*)&kr_[16 * 64 + xk1];                                \
      s = (f32x4){};                                                            \
      s = MFMA16(kfa, aq[0][0], s); s = MFMA16(kfb, aq[0][1], s); sa[1][0] = s; \
      s = (f32x4){};                                                            \
      s = MFMA16(kfa, aq[1][0], s); s = MFMA16(kfb, aq[1][1], s); sa[1][1] = s; \
    }                                                                           \
    __builtin_amdgcn_s_setprio(0);                                              \
    if (causal && kb_ + wk * 32 + 31 > qbase) {                                 \
      _Pragma("unroll")                                                         \
      for (int kblk = 0; kblk < 2; ++kblk)                                      \
        _Pragma("unroll")                                                       \
        for (int nb = 0; nb < 2; ++nb) {                                        \
          int key = kb_ + wk * 32 + kblk * 16 + quad * 4;                       \
          int q   = qbase + nb * 16 + fr;                                       \
          _Pragma("unroll")                                                     \
          for (int r = 0; r < 4; ++r)                                           \
            if (key + r > q) sa[kblk][nb][r] = MASKV;                           \
        }                                                                       \
    }                                                                           \
    float lm[2];                                                                \
    _Pragma("unroll")                                                           \
    for (int nb = 0; nb < 2; ++nb) {                                            \
      float m1 = max3f(sa[0][nb][0], sa[0][nb][1], sa[0][nb][2]);               \
      float m2 = max3f(sa[0][nb][3], sa[1][nb][0], sa[1][nb][1]);               \
      float m3 = max3f(sa[1][nb][2], sa[1][nb][3], m1);                         \
      lm[nb] = fmaxf(m2, m3);                                                   \
    }                                                                           \
    int ok = (lm[0] <= mrow[0] + 11.f) & (lm[1] <= mrow[1] + 11.f);             \
    if (!__all(ok)) {                                                           \
      _Pragma("unroll")                                                         \
      for (int nb = 0; nb < 2; ++nb) {                                          \
        float mx = lm[nb];                                                      \
        mx = fmaxf(mx, __shfl_xor(mx, 16));                                     \
        mx = fmaxf(mx, __shfl_xor(mx, 32));                                     \
        float mnew = fmaxf(mrow[nb], mx);                                       \
        float a = __builtin_amdgcn_exp2f(mrow[nb] - mnew);                      \
        mrow[nb] = mnew;                                                        \
        _Pragma("unroll")                                                       \
        for (int r = 0; r < 4; ++r) {                                           \
          float ar = __shfl(a, (lane & 48) | (quad * 4 + r));                   \
          oacc[nb][0][r] *= ar; oacc[nb][1][r] *= ar;                           \
          oacc[nb][2][r] *= ar; oacc[nb][3][r] *= ar;                           \
          oaccl[nb][r]   *= ar;                                                 \
        }                                                                       \
      }                                                                         \
    }                                                                           \
    bf16x8 pa32[2];                                                             \
    _Pragma("unroll")                                                           \
    for (int nb = 0; nb < 2; ++nb) {                                            \
      u32x4 pw;                                                                 \
      _Pragma("unroll")                                                         \
      for (int kblk = 0; kblk < 2; ++kblk) {                                    \
        float p0 = __builtin_amdgcn_exp2f(sa[kblk][nb][0] - mrow[nb]);          \
        float p1 = __builtin_amdgcn_exp2f(sa[kblk][nb][1] - mrow[nb]);          \
        float p2 = __builtin_amdgcn_exp2f(sa[kblk][nb][2] - mrow[nb]);          \
        float p3 = __builtin_amdgcn_exp2f(sa[kblk][nb][3] - mrow[nb]);          \
        pw[kblk * 2 + 0] = f2bf2(p0, p1);                                       \
        pw[kblk * 2 + 1] = f2bf2(p2, p3);                                       \
      }                                                                         \
      pa32[nb] = __builtin_bit_cast(bf16x8, pw);                                \
    }                                                                           \
    __builtin_amdgcn_s_setprio(1);                                              \
    oaccl[0] = MFMA16(pa32[0], vones, oaccl[0]);                                \
    oaccl[1] = MFMA16(pa32[1], vones, oaccl[1]);                                \
    {                                                                           \
      const u16* vr_ = (CUR) ? vB1 : vB0;                                       \
      _Pragma("unroll")                                                         \
      for (int db = 0; db < 4; ++db) {                                          \
        bf16x8 vv = *(const bf16x8*)&vr_[db * 16 * 64];                         \
        oacc[0][db] = MFMA16(pa32[0], vv, oacc[0][db]);                         \
        oacc[1][db] = MFMA16(pa32[1], vv, oacc[1][db]);                         \
      }                                                                         \
    }                                                                           \
    __builtin_amdgcn_s_setprio(0);                                              \
    __syncthreads();                                                            \
  } while (0)

__global__ __launch_bounds__(256, 5)
void attn_kernel(const u16* __restrict__ Q, const u16* __restrict__ K,
                 const u16* __restrict__ Vt, u16* __restrict__ O, int causal)
{
  __shared__ u16 KV[4][64 * 64];   // [0,1]=K dbuf, [2,3]=V dbuf; merge reuses as f32
  const int lane = threadIdx.x & 63, wid = threadIdx.x >> 6;
  const int fr = lane & 15, quad = lane >> 4;
  const int wq = wid >> 1, wk = wid & 1;

  const int flat = blockIdx.x;
  int bh, qb0, qb1, ntiles;
  if (causal) {                     // [bh_hi:3][pair:4][xcd:3]
    bh = ((flat >> 7) << 3) | (flat & 7);
    const int pair = (flat >> 3) & 15;
    qb0 = 31 - pair; qb1 = pair; ntiles = 2;
  } else {                          // [bh_hi:3][qb:5][xcd:3]
    bh = ((flat >> 8) << 3) | (flat & 7);
    qb0 = (flat >> 3) & 31; qb1 = 0; ntiles = 1;
  }
  const int b = bh >> 4, h = bh & 15;

  // constant all-ones B-frag (bf16 1.0 = 0x3F80)
  const short one = (short)0x3F80;
  const bf16x8 vones = {one, one, one, one, one, one, one, one};

  // loop-invariant swizzled LDS element offsets + hoisted per-buffer bases
  const int xk0 = ((quad    ) ^ (fr & 7)) * 8;
  const int xk1 = ((quad + 4) ^ (fr & 7)) * 8;
  const int xv  = ((wk * 4 + quad) ^ (fr & 7)) * 8;
  const u16* kB0 = &KV[0][(wk * 32 + fr) * 64];
  const u16* kB1 = &KV[1][(wk * 32 + fr) * 64];
  const u16* vB0 = &KV[2][fr * 64 + xv];
  const u16* vB1 = &KV[3][fr * 64 + xv];

  const int srow = wid * 16 + (lane >> 3);
  const int jg = (lane & 7) ^ (srow & 7);   // same for srow and srow+8
  const u16* kg = K + (size_t)b * SEQ * DMODEL + h * HDIM;
  const u16* vg = Vt + (size_t)bh * HDIM * SEQ;
  const u16* ks0 = kg + (size_t)srow * DMODEL + jg * 8;
  const u16* vs0 = vg + (size_t)srow * SEQ + jg * 8;
  float* mbuf = (float*)&KV[0][0];          // merge scratch (25.6KB < 32KB)

  for (int tile = 0; tile < ntiles; ++tile) {
    const int qb = tile == 0 ? qb0 : qb1;
    const int q0 = qb * 64;
    const int qbase = q0 + wq * 32;

    bf16x8 aq[2][2];
#pragma unroll
    for (int nb = 0; nb < 2; ++nb) {
      const u16* qp = Q + (size_t)(b * SEQ + qbase + nb * 16 + fr) * DMODEL + h * HDIM + quad * 8;
      aq[nb][0] = *(const bf16x8*)qp;
      aq[nb][1] = *(const bf16x8*)(qp + 32);
    }

    f32x4 oacc[2][4] = {};
    f32x4 oaccl[2] = {};              // MFMA-accumulated row sums (replicated cols)
    float mrow[2] = {-1e30f, -1e30f};

    const int nsteps = (causal ? (q0 + 64) : SEQ) >> 6;

    // prologue: stage tile 0 into bufs {0, 2}
    gload16(ks0,              &KV[0][(wid * 16 + 0) * 64]);
    gload16(ks0 + 8 * DMODEL, &KV[0][(wid * 16 + 8) * 64]);
    gload16(vs0,              &KV[2][(wid * 16 + 0) * 64]);
    gload16(vs0 + 8 * SEQ,    &KV[2][(wid * 16 + 8) * 64]);
    const u16* kpre = ks0 + 64 * DMODEL;
    const u16* vpre = vs0 + 64;
    __syncthreads();

    int t = 0;
    while (t + 2 <= nsteps) {
      ATTN_STEP(0, t);
      ATTN_STEP(1, t + 1);
      t += 2;
    }
    if (t < nsteps) ATTN_STEP(0, t);

    // ---- tile epilogue: 2-way split-K merge across wk (l free from oaccl) ----
    float mr2[2][4];
#pragma unroll
    for (int nb = 0; nb < 2; ++nb)
#pragma unroll
      for (int r = 0; r < 4; ++r) {
        int src = (lane & 48) | (quad * 4 + r);
        mr2[nb][r] = __shfl(mrow[nb], src);
      }
    float* mp = mbuf + (size_t)(wq * 64 + lane) * 50;
    if (wk) {
#pragma unroll
      for (int nb = 0; nb < 2; ++nb)
#pragma unroll
        for (int db = 0; db < 4; ++db) {
          *(float2*)&mp[(nb * 4 + db) * 4 + 0] = make_float2(oacc[nb][db][0], oacc[nb][db][1]);
          *(float2*)&mp[(nb * 4 + db) * 4 + 2] = make_float2(oacc[nb][db][2], oacc[nb][db][3]);
        }
#pragma unroll
      for (int nb = 0; nb < 2; ++nb) {
        *(float2*)&mp[32 + nb * 4 + 0] = make_float2(mr2[nb][0], mr2[nb][1]);
        *(float2*)&mp[32 + nb * 4 + 2] = make_float2(mr2[nb][2], mr2[nb][3]);
        *(float2*)&mp[40 + nb * 4 + 0] = make_float2(oaccl[nb][0], oaccl[nb][1]);
        *(float2*)&mp[40 + nb * 4 + 2] = make_float2(oaccl[nb][2], oaccl[nb][3]);
      }
    }
    __syncthreads();
    if (!wk) {
      float w0[2][4], w1[2][4];
#pragma unroll
      for (int nb = 0; nb < 2; ++nb)
#pragma unroll
        for (int r = 0; r < 4; ++r) {
          float m1 = mp[32 + nb * 4 + r];
          float l1 = mp[40 + nb * 4 + r];
          float M  = fmaxf(mr2[nb][r], m1);
          float c0 = __builtin_amdgcn_exp2f(mr2[nb][r] - M);
          float c1 = __builtin_amdgcn_exp2f(m1 - M);
          float inv = 1.0f / (oaccl[nb][r] * c0 + l1 * c1);
          w0[nb][r] = c0 * inv;
          w1[nb][r] = c1 * inv;
        }
#pragma unroll
      for (int nb = 0; nb < 2; ++nb) {
        u16* op = O + (size_t)(b * SEQ + qbase + nb * 16 + quad * 4) * DMODEL + h * HDIM + fr;
#pragma unroll
        for (int db = 0; db < 4; ++db) {
          float2 oa = *(float2*)&mp[(nb * 4 + db) * 4 + 0];
          float2 ob = *(float2*)&mp[(nb * 4 + db) * 4 + 2];
          float o1[4] = {oa.x, oa.y, ob.x, ob.y};
#pragma unroll
          for (int r = 0; r < 4; ++r)
            op[(size_t)r * DMODEL + db * 16] =
                f2bf(oacc[nb][db][r] * w0[nb][r] + o1[r] * w1[nb][r]);
        }
      }
    }
    __syncthreads();   // merge reads done before next tile's staging reuses KV
  }
}

// ---------------- launcher ----------------
extern "C" void kernel_launch(void* const* d_in, const int* in_sizes, int n_in,
                              void* d_out, int out_size, void* d_ws, size_t ws_size,
                              hipStream_t stream)
{
  const float* x   = (const float*)d_in[0];
  const float* ek  = (const float*)d_in[1];
  const float* ev  = (const float*)d_in[2];
  const float* Wq1 = (const float*)d_in[3];
  const float* bq1 = (const float*)d_in[4];
  const float* Wk1 = (const float*)d_in[5];
  const float* bk1 = (const float*)d_in[6];
  const float* Wv1 = (const float*)d_in[7];
  const float* bv1 = (const float*)d_in[8];
  const float* Wo1 = (const float*)d_in[9];
  const float* bo1 = (const float*)d_in[10];
  const float* Wq2 = (const float*)d_in[11];
  const float* bq2 = (const float*)d_in[12];
  const float* Wk2 = (const float*)d_in[13];
  const float* bk2 = (const float*)d_in[14];
  const float* Wv2 = (const float*)d_in[15];
  const float* bv2 = (const float*)d_in[16];
  const float* Wo2 = (const float*)d_in[17];
  const float* bo2 = (const float*)d_in[18];

  char* ws = (char*)d_ws;
  u16* wt  = (u16*)ws;
  u16* xb  = (u16*)(ws + (16u << 20));
  u16* ekb = (u16*)(ws + (32u << 20));
  u16* evb = (u16*)(ws + (48u << 20));
  u16* qb  = (u16*)(ws + (64u << 20));
  u16* kkb = (u16*)(ws + (80u << 20));
  u16* vtb = (u16*)(ws + (96u << 20));
  u16* hb  = (u16*)(ws + (112u << 20));
  u16* ob  = xb;   // x dead after layer-1 projections

  const int n4 = MTOT * DMODEL / 4;
  const float qscale = 0.125f * 1.4426950408889634f;   // 1/sqrt(HD) * log2(e)

  pack_act3<<<dim3(n4 / 256, 3), 256, 0, stream>>>(x, ek, ev, xb, ekb, evb, n4);
  pack_w8<<<dim3(16, 16, 8), 256, 0, stream>>>(Wq1, Wk1, Wv1, Wo1, Wq2, Wk2, Wv2, Wo2, wt);

  const int gblocks = (MTOT / 128) * (DMODEL / 128);   // 512, XCD-swizzled in-kernel
  const int ablocks_causal = (SEQ / 128) * BSZ * NHEAD; // 1024 pair-blocks
  const int ablocks_cross  = (SEQ / 64) * BSZ * NHEAD;  // 2048 single-tile blocks

  // layer 1: causal self-attention
  gemm_qkv<<<3 * gblocks, 256, 0, stream>>>(xb, xb, xb, wt, bq1, bk1, bv1,
                                            qb, kkb, vtb, qscale);
  attn_kernel<<<ablocks_causal, 256, 0, stream>>>(qb, kkb, vtb, ob, 1);
  gemm_bt<<<gblocks, 256, 0, stream>>>(ob, wt + 3 * NW, bo1, hb, 1.0f, 0);

  // layer 2: cross attention
  gemm_qkv<<<3 * gblocks, 256, 0, stream>>>(hb, ekb, evb, wt + 4 * NW, bq2, bk2, bv2,
                                            qb, kkb, vtb, qscale);
  attn_kernel<<<ablocks_cross, 256, 0, stream>>>(qb, kkb, vtb, ob, 0);
  gemm_bt<<<gblocks, 256, 0, stream>>>(ob, wt + 7 * NW, bo2, d_out, 1.0f, 2);
}

// Round 18
// 354.081 us; speedup vs baseline: 1.1805x; 1.1805x over previous
//
#include <hip/hip_runtime.h>
#include <hip/hip_bf16.h>
#include <cstdint>

typedef unsigned short u16;
typedef unsigned int   u32;
typedef __attribute__((ext_vector_type(8))) short bf16x8;   // 8 bf16 = 4 VGPRs
typedef __attribute__((ext_vector_type(4))) u32  u32x4;
typedef __attribute__((ext_vector_type(4))) float f32x4;

#define MFMA16(a,b,c)    __builtin_amdgcn_mfma_f32_16x16x32_bf16((a),(b),(c),0,0,0)

#define BSZ    4
#define SEQ    2048
#define DMODEL 1024
#define NHEAD  16
#define HDIM   64
#define MTOT   (BSZ*SEQ)   // 8192
#define MASKV  (-3.0e38f)  // finite: exp2(MASKV - m) == 0, no inf-inf NaN
#define NW     (DMODEL*DMODEL)

// native conversion (RNE)
__device__ __forceinline__ u16 f2bf(float f) {
  __hip_bfloat16 h = __float2bfloat16(f);
  return __builtin_bit_cast(u16, h);
}
// paired conversion -> v_cvt_pk_bf16_f32 (RNE)
__device__ __forceinline__ u32 f2bf2(float a, float b) {
  __hip_bfloat162 h = __float22bfloat162_rn(make_float2(a, b));
  u32 u; __builtin_memcpy(&u, &h, sizeof(u));
  return u;
}
// fmax-of-3 -> v_max3_f32
__device__ __forceinline__ float max3f(float a, float b, float c) {
  return fmaxf(fmaxf(a, b), c);
}

typedef __attribute__((address_space(1))) void g1v;
typedef __attribute__((address_space(3))) void l3v;
// async global->LDS, 16B/lane. LDS dest is wave-uniform base (HW adds lane*16B).
__device__ __forceinline__ void gload16(const void* g, void* l) {
  __builtin_amdgcn_global_load_lds((g1v*)(uintptr_t)g, (l3v*)(u32)(uintptr_t)l, 16, 0, 0);
}

// ---------------- pack: fp32 -> bf16 activations (x, ek, ev in one launch) ----------
__global__ void pack_act3(const float* __restrict__ x, const float* __restrict__ ek,
                          const float* __restrict__ ev, u16* __restrict__ xb,
                          u16* __restrict__ ekb, u16* __restrict__ evb, int n4) {
  int i = blockIdx.x * blockDim.x + threadIdx.x;
  if (i >= n4) return;
  const float* in; u16* out;
  if (blockIdx.y == 0)      { in = x;  out = xb;  }
  else if (blockIdx.y == 1) { in = ek; out = ekb; }
  else                      { in = ev; out = evb; }
  float4 v = ((const float4*)in)[i];
  ((uint2*)out)[i] = make_uint2(f2bf2(v.x, v.y), f2bf2(v.z, v.w));
}

// ---------------- pack: all 8 weights -> Bt[n][k] bf16 in one launch ----------------
__global__ void pack_w8(const float* __restrict__ w0, const float* __restrict__ w1,
                        const float* __restrict__ w2, const float* __restrict__ w3,
                        const float* __restrict__ w4, const float* __restrict__ w5,
                        const float* __restrict__ w6, const float* __restrict__ w7,
                        u16* __restrict__ wt) {
  __shared__ float tile[64][65];
  const int w = blockIdx.z;
  const float* src;
  switch (w) {
    case 0: src = w0; break; case 1: src = w1; break;
    case 2: src = w2; break; case 3: src = w3; break;
    case 4: src = w4; break; case 5: src = w5; break;
    case 6: src = w6; break; default: src = w7; break;
  }
  const int per_head = (w == 3 || w == 7) ? 0 : 1;
  u16* dst = wt + (size_t)w * NW;
  int kt = blockIdx.x * 64, nt = blockIdx.y * 64;
  int tx = threadIdx.x & 63, ty = threadIdx.x >> 6;
  for (int kk = ty; kk < 64; kk += 4) {
    int k = kt + kk, n = nt + tx;
    float v = per_head ? src[(size_t)(n >> 6) * (DMODEL * HDIM) + (size_t)k * HDIM + (n & 63)]
                       : src[(size_t)k * DMODEL + n];
    tile[kk][tx] = v;
  }
  __syncthreads();
  for (int nn = ty; nn < 64; nn += 4)
    dst[(size_t)(nt + nn) * DMODEL + kt + tx] = f2bf(tile[tx][nn]);
}

// ---------------- GEMM core (BK=64 double-buffered 2-phase prefetch) ----------------
// epi: 0 = bf16 [M][N]; 1 = bf16 Vt s-permuted; 2 = f32 [M][N]
template <bool TMPL>
__device__ __forceinline__ void gemm_body(const u16* __restrict__ A, const u16* __restrict__ Bt,
                                          const float* __restrict__ bias, void* __restrict__ Cout,
                                          float scale, int epi, int inner)
{
  __shared__ u16 As[2][128 * 64];
  __shared__ u16 Bs[2][128 * 64];
  const int lane = threadIdx.x & 63, wid = threadIdx.x >> 6;
  const int wg = ((inner & 7) << 6) | (inner >> 3);  // [xcd:3][seq:6]
  const int m0 = (wg >> 3) * 128, n0 = (wg & 7) * 128;

  const int srow = wid * 32 + (lane >> 3);          // +i*8; (row&7) == lane>>3
  const int sc = (lane & 7) ^ ((lane >> 3) & 7);    // pre-swizzled source chunk
  const u16* gA = A  + (size_t)(m0 + srow) * DMODEL + sc * 8;
  const u16* gB = Bt + (size_t)(n0 + srow) * DMODEL + sc * 8;

  const int fr = lane & 15, quad = lane >> 4;
  const int wr = (wid >> 1) * 64, wc = (wid & 1) * 64;

  f32x4 acc[4][4] = {};
  const int NT = DMODEL / 64;   // 16

#pragma unroll
  for (int i = 0; i < 4; ++i) {
    gload16(gA + (size_t)(i * 8) * DMODEL, &As[0][(wid * 32 + i * 8) * 64]);
    gload16(gB + (size_t)(i * 8) * DMODEL, &Bs[0][(wid * 32 + i * 8) * 64]);
  }
  gA += 64; gB += 64;
  __syncthreads();

  for (int kt = 0; kt < NT; ++kt) {
    const int cur = kt & 1;
    if (kt + 1 < NT) {
#pragma unroll
      for (int i = 0; i < 4; ++i) {
        gload16(gA + (size_t)(i * 8) * DMODEL, &As[cur ^ 1][(wid * 32 + i * 8) * 64]);
        gload16(gB + (size_t)(i * 8) * DMODEL, &Bs[cur ^ 1][(wid * 32 + i * 8) * 64]);
      }
      gA += 64; gB += 64;
    }
#pragma unroll
    for (int kp = 0; kp < 2; ++kp) {
      bf16x8 af[4], bfr[4];
#pragma unroll
      for (int i = 0; i < 4; ++i) {
        int ra = wr + i * 16 + fr;
        af[i]  = *(const bf16x8*)&As[cur][ra * 64 + (((kp * 4 + quad) ^ (ra & 7)) * 8)];
        int rb = wc + i * 16 + fr;
        bfr[i] = *(const bf16x8*)&Bs[cur][rb * 64 + (((kp * 4 + quad) ^ (rb & 7)) * 8)];
      }
#pragma unroll
      for (int i = 0; i < 4; ++i)
#pragma unroll
        for (int j = 0; j < 4; ++j)
          acc[i][j] = MFMA16(af[i], bfr[j], acc[i][j]);
    }
    __syncthreads();   // buf[cur] reads done; buf[cur^1] staging drained
  }

  // C/D layout: col = lane&15, row = (lane>>4)*4 + reg
#pragma unroll
  for (int i = 0; i < 4; ++i) {
    int row0 = m0 + wr + i * 16 + quad * 4;
#pragma unroll
    for (int j = 0; j < 4; ++j) {
      int col = n0 + wc + j * 16 + fr;
      float bv = bias[col];
      float v0 = (acc[i][j][0] + bv) * scale, v1 = (acc[i][j][1] + bv) * scale;
      float v2 = (acc[i][j][2] + bv) * scale, v3 = (acc[i][j][3] + bv) * scale;
      if (epi == 2) {
        float* C = (float*)Cout;
        C[(size_t)(row0 + 0) * DMODEL + col] = v0;
        C[(size_t)(row0 + 1) * DMODEL + col] = v1;
        C[(size_t)(row0 + 2) * DMODEL + col] = v2;
        C[(size_t)(row0 + 3) * DMODEL + col] = v3;
      } else if (epi == 0) {
        u16* C = (u16*)Cout;
        C[(size_t)(row0 + 0) * DMODEL + col] = f2bf(v0);
        C[(size_t)(row0 + 1) * DMODEL + col] = f2bf(v1);
        C[(size_t)(row0 + 2) * DMODEL + col] = f2bf(v2);
        C[(size_t)(row0 + 3) * DMODEL + col] = f2bf(v3);
      } else {
        u16* C = (u16*)Cout;
        int bi = row0 >> 11, s = row0 & 2047;
        // permuted s within 32-group: (b:1|c:2|r:2) -> (c:2|b:1|r:2)
        int sN = (s & ~31) | (((s >> 2) & 3) << 3) | (((s >> 4) & 1) << 2) | (s & 3);
        size_t vtr = ((size_t)(bi * NHEAD + (col >> 6)) * HDIM + (col & 63)) * SEQ + sN;
        *(uint2*)&C[vtr] = make_uint2(f2bf2(v0, v1), f2bf2(v2, v3));
      }
    }
  }
}

// single GEMM (Wo projections, final output)
__global__ __launch_bounds__(256, 2)
void gemm_bt(const u16* __restrict__ A, const u16* __restrict__ Bt,
             const float* __restrict__ bias, void* __restrict__ Cout,
             float scale, int epi)
{
  gemm_body<true>(A, Bt, bias, Cout, scale, epi, blockIdx.x);
}

// fused Q/K/V projections: 3 x 512 blocks; seg = bid>>9 picks operands (uniform)
__global__ __launch_bounds__(256, 2)
void gemm_qkv(const u16* __restrict__ Aq, const u16* __restrict__ Ak,
              const u16* __restrict__ Av, const u16* __restrict__ Btb,
              const float* __restrict__ bq, const float* __restrict__ bk,
              const float* __restrict__ bv, void* __restrict__ oq,
              void* __restrict__ ok, void* __restrict__ ov, float qscale)
{
  const int seg = blockIdx.x >> 9, inner = blockIdx.x & 511;
  const u16* A; const float* bias; void* Cout; float scale; int epi;
  if (seg == 0)      { A = Aq; bias = bq; Cout = oq; scale = qscale; epi = 0; }
  else if (seg == 1) { A = Ak; bias = bk; Cout = ok; scale = 1.0f;   epi = 0; }
  else               { A = Av; bias = bv; Cout = ov; scale = 1.0f;   epi = 1; }
  gemm_body<true>(A, Btb + (size_t)seg * NW, bias, Cout, scale, epi, inner);
}

// ---------------- flash attention v14 (round-16 best-known config) ----------------
// Unroll-by-2 with compile-time CUR; hoisted base arrays; launch_bounds(256,4)
// (5 blocks/CU via (256,5) FORCES 48-VGPR allocation -> spills -> 418us; do not).
// Split-K waves 2x2, swapped QK^T, zero-shuffle P, K=32 PV, MFMA row-sum.
// Causal: 1024 paired blocks (uniform 33 steps). Cross: 2048 single-tile blocks.

#define ATTN_STEP(CUR, TT)                                                      \
  do {                                                                          \
    const int kb_ = (TT) * 64;                                                  \
    if ((TT) + 1 < nsteps) {                                                    \
      gload16(kpre,              &KV[(CUR) ^ 1][(wid * 16 + 0) * 64]);          \
      gload16(kpre + 8 * DMODEL, &KV[(CUR) ^ 1][(wid * 16 + 8) * 64]);          \
      gload16(vpre,              &KV[2 + ((CUR) ^ 1)][(wid * 16 + 0) * 64]);    \
      gload16(vpre + 8 * SEQ,    &KV[2 + ((CUR) ^ 1)][(wid * 16 + 8) * 64]);    \
      kpre += 64 * DMODEL; vpre += 64;                                          \
    }                                                                           \
    const u16* kr_ = krb[(CUR)];                                                \
    f32x4 sa[2][2];                                                             \
    __builtin_amdgcn_s_setprio(1);                                              \
    {                                                                           \
      bf16x8 kfa = *(const bf16x8*)&kr_[xk0];                                   \
      bf16x8 kfb = *(const bf16x8*)&kr_[xk1];                                   \
      f32x4 s = {};                                                             \
      s = MFMA16(kfa, aq[0][0], s); s = MFMA16(kfb, aq[0][1], s); sa[0][0] = s; \
      s = (f32x4){};                                                            \
      s = MFMA16(kfa, aq[1][0], s); s = MFMA16(kfb, aq[1][1], s); sa[0][1] = s; \
      kfa = *(const bf16x8*)&kr_[16 * 64 + xk0];                                \
      kfb = *(const bf16x8*)&kr_[16 * 64 + xk1];                                \
      s = (f32x4){};                                                            \
      s = MFMA16(kfa, aq[0][0], s); s = MFMA16(kfb, aq[0][1], s); sa[1][0] = s; \
      s = (f32x4){};                                                            \
      s = MFMA16(kfa, aq[1][0], s); s = MFMA16(kfb, aq[1][1], s); sa[1][1] = s; \
    }                                                                           \
    __builtin_amdgcn_s_setprio(0);                                              \
    if (causal && kb_ + wk * 32 + 31 > qbase) {                                 \
      _Pragma("unroll")                                                         \
      for (int kblk = 0; kblk < 2; ++kblk)                                      \
        _Pragma("unroll")                                                       \
        for (int nb = 0; nb < 2; ++nb) {                                        \
          int key = kb_ + wk * 32 + kblk * 16 + quad * 4;                       \
          int q   = qbase + nb * 16 + fr;                                       \
          _Pragma("unroll")                                                     \
          for (int r = 0; r < 4; ++r)                                           \
            if (key + r > q) sa[kblk][nb][r] = MASKV;                           \
        }                                                                       \
    }                                                                           \
    float lm[2];                                                                \
    _Pragma("unroll")                                                           \
    for (int nb = 0; nb < 2; ++nb) {                                            \
      float m1 = max3f(sa[0][nb][0], sa[0][nb][1], sa[0][nb][2]);               \
      float m2 = max3f(sa[0][nb][3], sa[1][nb][0], sa[1][nb][1]);               \
      float m3 = max3f(sa[1][nb][2], sa[1][nb][3], m1);                         \
      lm[nb] = fmaxf(m2, m3);                                                   \
    }                                                                           \
    int ok = (lm[0] <= mrow[0] + 11.f) & (lm[1] <= mrow[1] + 11.f);             \
    if (!__all(ok)) {                                                           \
      _Pragma("unroll")                                                         \
      for (int nb = 0; nb < 2; ++nb) {                                          \
        float mx = lm[nb];                                                      \
        mx = fmaxf(mx, __shfl_xor(mx, 16));                                     \
        mx = fmaxf(mx, __shfl_xor(mx, 32));                                     \
        float mnew = fmaxf(mrow[nb], mx);                                       \
        float a = __builtin_amdgcn_exp2f(mrow[nb] - mnew);                      \
        mrow[nb] = mnew;                                                        \
        _Pragma("unroll")                                                       \
        for (int r = 0; r < 4; ++r) {                                           \
          float ar = __shfl(a, (lane & 48) | (quad * 4 + r));                   \
          oacc[nb][0][r] *= ar; oacc[nb][1][r] *= ar;                           \
          oacc[nb][2][r] *= ar; oacc[nb][3][r] *= ar;                           \
          oaccl[nb][r]   *= ar;                                                 \
        }                                                                       \
      }                                                                         \
    }                                                                           \
    bf16x8 pa32[2];                                                             \
    _Pragma("unroll")                                                           \
    for (int nb = 0; nb < 2; ++nb) {                                            \
      u32x4 pw;                                                                 \
      _Pragma("unroll")                                                         \
      for (int kblk = 0; kblk < 2; ++kblk) {                                    \
        float p0 = __builtin_amdgcn_exp2f(sa[kblk][nb][0] - mrow[nb]);          \
        float p1 = __builtin_amdgcn_exp2f(sa[kblk][nb][1] - mrow[nb]);          \
        float p2 = __builtin_amdgcn_exp2f(sa[kblk][nb][2] - mrow[nb]);          \
        float p3 = __builtin_amdgcn_exp2f(sa[kblk][nb][3] - mrow[nb]);          \
        pw[kblk * 2 + 0] = f2bf2(p0, p1);                                       \
        pw[kblk * 2 + 1] = f2bf2(p2, p3);                                       \
      }                                                                         \
      pa32[nb] = __builtin_bit_cast(bf16x8, pw);                                \
    }                                                                           \
    __builtin_amdgcn_s_setprio(1);                                              \
    oaccl[0] = MFMA16(pa32[0], vones, oaccl[0]);                                \
    oaccl[1] = MFMA16(pa32[1], vones, oaccl[1]);                                \
    {                                                                           \
      const u16* vr_ = vrb[(CUR)];                                              \
      _Pragma("unroll")                                                         \
      for (int db = 0; db < 4; ++db) {                                          \
        bf16x8 vv = *(const bf16x8*)&vr_[db * 16 * 64];                         \
        oacc[0][db] = MFMA16(pa32[0], vv, oacc[0][db]);                         \
        oacc[1][db] = MFMA16(pa32[1], vv, oacc[1][db]);                         \
      }                                                                         \
    }                                                                           \
    __builtin_amdgcn_s_setprio(0);                                              \
    __syncthreads();                                                            \
  } while (0)

__global__ __launch_bounds__(256, 4)
void attn_kernel(const u16* __restrict__ Q, const u16* __restrict__ K,
                 const u16* __restrict__ Vt, u16* __restrict__ O, int causal)
{
  __shared__ u16 KV[4][64 * 64];   // [0,1]=K dbuf, [2,3]=V dbuf; merge reuses as f32
  const int lane = threadIdx.x & 63, wid = threadIdx.x >> 6;
  const int fr = lane & 15, quad = lane >> 4;
  const int wq = wid >> 1, wk = wid & 1;

  const int flat = blockIdx.x;
  int bh, qb0, qb1, ntiles;
  if (causal) {                     // [bh_hi:3][pair:4][xcd:3]
    bh = ((flat >> 7) << 3) | (flat & 7);
    const int pair = (flat >> 3) & 15;
    qb0 = 31 - pair; qb1 = pair; ntiles = 2;
  } else {                          // [bh_hi:3][qb:5][xcd:3]
    bh = ((flat >> 8) << 3) | (flat & 7);
    qb0 = (flat >> 3) & 31; qb1 = 0; ntiles = 1;
  }
  const int b = bh >> 4, h = bh & 15;

  // constant all-ones B-frag (bf16 1.0 = 0x3F80)
  const short one = (short)0x3F80;
  const bf16x8 vones = {one, one, one, one, one, one, one, one};

  // loop-invariant swizzled LDS element offsets + hoisted per-buffer bases
  const int xk0 = ((quad    ) ^ (fr & 7)) * 8;
  const int xk1 = ((quad + 4) ^ (fr & 7)) * 8;
  const int xv  = ((wk * 4 + quad) ^ (fr & 7)) * 8;
  const u16* krb[2] = { &KV[0][(wk * 32 + fr) * 64], &KV[1][(wk * 32 + fr) * 64] };
  const u16* vrb[2] = { &KV[2][fr * 64 + xv],        &KV[3][fr * 64 + xv] };

  const int srow = wid * 16 + (lane >> 3);
  const int jg = (lane & 7) ^ (srow & 7);   // same for srow and srow+8
  const u16* kg = K + (size_t)b * SEQ * DMODEL + h * HDIM;
  const u16* vg = Vt + (size_t)bh * HDIM * SEQ;
  const u16* ks0 = kg + (size_t)srow * DMODEL + jg * 8;
  const u16* vs0 = vg + (size_t)srow * SEQ + jg * 8;
  float* mbuf = (float*)&KV[0][0];          // merge scratch (25.6KB < 32KB)

  for (int tile = 0; tile < ntiles; ++tile) {
    const int qb = tile == 0 ? qb0 : qb1;
    const int q0 = qb * 64;
    const int qbase = q0 + wq * 32;

    bf16x8 aq[2][2];
#pragma unroll
    for (int nb = 0; nb < 2; ++nb) {
      const u16* qp = Q + (size_t)(b * SEQ + qbase + nb * 16 + fr) * DMODEL + h * HDIM + quad * 8;
      aq[nb][0] = *(const bf16x8*)qp;
      aq[nb][1] = *(const bf16x8*)(qp + 32);
    }

    f32x4 oacc[2][4] = {};
    f32x4 oaccl[2] = {};              // MFMA-accumulated row sums (replicated cols)
    float mrow[2] = {-1e30f, -1e30f};

    const int nsteps = (causal ? (q0 + 64) : SEQ) >> 6;

    // prologue: stage tile 0 into bufs {0, 2}
    gload16(ks0,              &KV[0][(wid * 16 + 0) * 64]);
    gload16(ks0 + 8 * DMODEL, &KV[0][(wid * 16 + 8) * 64]);
    gload16(vs0,              &KV[2][(wid * 16 + 0) * 64]);
    gload16(vs0 + 8 * SEQ,    &KV[2][(wid * 16 + 8) * 64]);
    const u16* kpre = ks0 + 64 * DMODEL;
    const u16* vpre = vs0 + 64;
    __syncthreads();

    int t = 0;
    while (t + 2 <= nsteps) {
      ATTN_STEP(0, t);
      ATTN_STEP(1, t + 1);
      t += 2;
    }
    if (t < nsteps) ATTN_STEP(0, t);

    // ---- tile epilogue: 2-way split-K merge across wk (l free from oaccl) ----
    float mr2[2][4];
#pragma unroll
    for (int nb = 0; nb < 2; ++nb)
#pragma unroll
      for (int r = 0; r < 4; ++r) {
        int src = (lane & 48) | (quad * 4 + r);
        mr2[nb][r] = __shfl(mrow[nb], src);
      }
    float* mp = mbuf + (size_t)(wq * 64 + lane) * 50;
    if (wk) {
#pragma unroll
      for (int nb = 0; nb < 2; ++nb)
#pragma unroll
        for (int db = 0; db < 4; ++db) {
          *(float2*)&mp[(nb * 4 + db) * 4 + 0] = make_float2(oacc[nb][db][0], oacc[nb][db][1]);
          *(float2*)&mp[(nb * 4 + db) * 4 + 2] = make_float2(oacc[nb][db][2], oacc[nb][db][3]);
        }
#pragma unroll
      for (int nb = 0; nb < 2; ++nb) {
        *(float2*)&mp[32 + nb * 4 + 0] = make_float2(mr2[nb][0], mr2[nb][1]);
        *(float2*)&mp[32 + nb * 4 + 2] = make_float2(mr2[nb][2], mr2[nb][3]);
        *(float2*)&mp[40 + nb * 4 + 0] = make_float2(oaccl[nb][0], oaccl[nb][1]);
        *(float2*)&mp[40 + nb * 4 + 2] = make_float2(oaccl[nb][2], oaccl[nb][3]);
      }
    }
    __syncthreads();
    if (!wk) {
      float w0[2][4], w1[2][4];
#pragma unroll
      for (int nb = 0; nb < 2; ++nb)
#pragma unroll
        for (int r = 0; r < 4; ++r) {
          float m1 = mp[32 + nb * 4 + r];
          float l1 = mp[40 + nb * 4 + r];
          float M  = fmaxf(mr2[nb][r], m1);
          float c0 = __builtin_amdgcn_exp2f(mr2[nb][r] - M);
          float c1 = __builtin_amdgcn_exp2f(m1 - M);
          float inv = 1.0f / (oaccl[nb][r] * c0 + l1 * c1);
          w0[nb][r] = c0 * inv;
          w1[nb][r] = c1 * inv;
        }
#pragma unroll
      for (int nb = 0; nb < 2; ++nb) {
        u16* op = O + (size_t)(b * SEQ + qbase + nb * 16 + quad * 4) * DMODEL + h * HDIM + fr;
#pragma unroll
        for (int db = 0; db < 4; ++db) {
          float2 oa = *(float2*)&mp[(nb * 4 + db) * 4 + 0];
          float2 ob = *(float2*)&mp[(nb * 4 + db) * 4 + 2];
          float o1[4] = {oa.x, oa.y, ob.x, ob.y};
#pragma unroll
          for (int r = 0; r < 4; ++r)
            op[(size_t)r * DMODEL + db * 16] =
                f2bf(oacc[nb][db][r] * w0[nb][r] + o1[r] * w1[nb][r]);
        }
      }
    }
    __syncthreads();   // merge reads done before next tile's staging reuses KV
  }
}

// ---------------- launcher ----------------
extern "C" void kernel_launch(void* const* d_in, const int* in_sizes, int n_in,
                              void* d_out, int out_size, void* d_ws, size_t ws_size,
                              hipStream_t stream)
{
  const float* x   = (const float*)d_in[0];
  const float* ek  = (const float*)d_in[1];
  const float* ev  = (const float*)d_in[2];
  const float* Wq1 = (const float*)d_in[3];
  const float* bq1 = (const float*)d_in[4];
  const float* Wk1 = (const float*)d_in[5];
  const float* bk1 = (const float*)d_in[6];
  const float* Wv1 = (const float*)d_in[7];
  const float* bv1 = (const float*)d_in[8];
  const float* Wo1 = (const float*)d_in[9];
  const float* bo1 = (const float*)d_in[10];
  const float* Wq2 = (const float*)d_in[11];
  const float* bq2 = (const float*)d_in[12];
  const float* Wk2 = (const float*)d_in[13];
  const float* bk2 = (const float*)d_in[14];
  const float* Wv2 = (const float*)d_in[15];
  const float* bv2 = (const float*)d_in[16];
  const float* Wo2 = (const float*)d_in[17];
  const float* bo2 = (const float*)d_in[18];

  char* ws = (char*)d_ws;
  u16* wt  = (u16*)ws;
  u16* xb  = (u16*)(ws + (16u << 20));
  u16* ekb = (u16*)(ws + (32u << 20));
  u16* evb = (u16*)(ws + (48u << 20));
  u16* qb  = (u16*)(ws + (64u << 20));
  u16* kkb = (u16*)(ws + (80u << 20));
  u16* vtb = (u16*)(ws + (96u << 20));
  u16* hb  = (u16*)(ws + (112u << 20));
  u16* ob  = xb;   // x dead after layer-1 projections

  const int n4 = MTOT * DMODEL / 4;
  const float qscale = 0.125f * 1.4426950408889634f;   // 1/sqrt(HD) * log2(e)

  pack_act3<<<dim3(n4 / 256, 3), 256, 0, stream>>>(x, ek, ev, xb, ekb, evb, n4);
  pack_w8<<<dim3(16, 16, 8), 256, 0, stream>>>(Wq1, Wk1, Wv1, Wo1, Wq2, Wk2, Wv2, Wo2, wt);

  const int gblocks = (MTOT / 128) * (DMODEL / 128);   // 512, XCD-swizzled in-kernel
  const int ablocks_causal = (SEQ / 128) * BSZ * NHEAD; // 1024 pair-blocks
  const int ablocks_cross  = (SEQ / 64) * BSZ * NHEAD;  // 2048 single-tile blocks

  // layer 1: causal self-attention
  gemm_qkv<<<3 * gblocks, 256, 0, stream>>>(xb, xb, xb, wt, bq1, bk1, bv1,
                                            qb, kkb, vtb, qscale);
  attn_kernel<<<ablocks_causal, 256, 0, stream>>>(qb, kkb, vtb, ob, 1);
  gemm_bt<<<gblocks, 256, 0, stream>>>(ob, wt + 3 * NW, bo1, hb, 1.0f, 0);

  // layer 2: cross attention
  gemm_qkv<<<3 * gblocks, 256, 0, stream>>>(hb, ekb, evb, wt + 4 * NW, bq2, bk2, bv2,
                                            qb, kkb, vtb, qscale);
  attn_kernel<<<ablocks_cross, 256, 0, stream>>>(qb, kkb, vtb, ob, 0);
  gemm_bt<<<gblocks, 256, 0, stream>>>(ob, wt + 7 * NW, bo2, d_out, 1.0f, 2);
}